// Round 1
// baseline (211.286 us; speedup 1.0000x reference)
//
#include <hip/hip_runtime.h>
#include <hip/hip_bf16.h>

// EGCL (EGNN layer): N=384 nodes, V=32 vectors, H=128 feats, U=256 width.
// E = N*(N-1) = 147072 fully-connected edges. f32 in/out, bf16 MFMA compute.
// Edges grouped by RECEIVER r: segment sums are in-block reductions.
// R17 (R16 base):
//  - svecg hoist: nf[s] @ We1[32:160] precomputed per SENDER (like cvecg for
//    receivers) -> gemm1 K shrinks 160->32 (KT=2), nf staging pass deleted,
//    per-edge svec added in the gemm1 epilogue (16 coalesced f32 loads/lane).
//  - MM 64->32: LDS/block 71.2KB -> 33.9KB (sred aliased into dead Bb)
//    -> 4 blocks/CU (was 2), __launch_bounds__(512,8) for 8 waves/SIMD.
//    Theory: kernel was latency-bound (Mfma 26%, VALU 47%, occ 40%); 2x
//    resident waves to push VALU busy toward its ~58us serial floor.
//  - mi pass: 256 threads x 32 edges -> atomic count unchanged vs R16.

#define NN 384
#define VV 32
#define HH 128
#define UU 256
#define MM 32            // edges per block
#define NCHUNK 12        // 12*32 = 384 = 383 edges + 1 pad
#define SS 264           // LDS row stride edge buffers (256-wide, +8 pad)
#define XS 392           // node xs row stride (384-wide, +8 pad)

typedef __bf16 bf16v8 __attribute__((ext_vector_type(8)));
typedef __bf16 bf16v4 __attribute__((ext_vector_type(4)));
typedef float  f32x4  __attribute__((ext_vector_type(4)));
typedef float  f32x16 __attribute__((ext_vector_type(16)));

__device__ __forceinline__ float fast_rcp(float x) { return __builtin_amdgcn_rcpf(x); }
__device__ __forceinline__ float fast_sqrt(float x) { return __builtin_amdgcn_sqrtf(x); }
__device__ __forceinline__ float fast_silu(float v) {
    return v * __builtin_amdgcn_rcpf(1.f + __expf(-v));
}

// ---------------- repack + cvec/svec + accumulator zeroing -----------------
// blocks [0,180): fmt32 LDS-tiled transpose  P[kt][n][kk]=W[kt*16+kk][n]*s
//   We1 only needs k rows 0..31 now (len2 block) -> 4 tiles.
// blocks [180,340): scalar fmt16 (Wxl, Whl)
// blocks [340,724): cvecg[r][n] = sum_k nf[r][k]*We1[160+k][n]*s288
// blocks [724,1108): svecg[s][n] = sum_k nf[s][k]*We1[ 32+k][n]*s288
// blocks [1108,1240): zero mi[384*256]+shift[384*96] (float4 stores)
__global__ __launch_bounds__(256)
void repack_all(const float* __restrict__ We1, const float* __restrict__ We2,
                const float* __restrict__ Wx1, const float* __restrict__ Wx2,
                const float* __restrict__ Wh1, const float* __restrict__ Wh2,
                const float* __restrict__ Wxl, const float* __restrict__ Whl,
                const float* __restrict__ nf,
                __bf16* __restrict__ we1p, __bf16* __restrict__ we2p,
                __bf16* __restrict__ wx1p, __bf16* __restrict__ wx2p,
                __bf16* __restrict__ wh1p, __bf16* __restrict__ wh2p,
                __bf16* __restrict__ wxlp, __bf16* __restrict__ whlp,
                float* __restrict__ cvecg, float* __restrict__ svecg,
                float* __restrict__ zbase) {
    const float s288 = 0.05892556509887896f;   // 1/sqrt(288)
    const float s384 = 0.05103103630798288f;   // 1/sqrt(384)
    const float s16  = 0.0625f;
    const int b   = blockIdx.x;
    const int tid = threadIdx.x;

    if (b < 180) {                               // ---- fmt32 transpose tiles
        __shared__ __bf16 T[32 * 72];
        const float* src; __bf16* dst; int tile; float scale;
        if (b < 4)        { src = We1; dst = we1p; tile = b;       scale = s288; }
        else if (b < 36)  { src = We2; dst = we2p; tile = b - 4;   scale = s16;  }
        else if (b < 68)  { src = Wx1; dst = wx1p; tile = b - 36;  scale = s16;  }
        else if (b < 100) { src = Wx2; dst = wx2p; tile = b - 68;  scale = s16;  }
        else if (b < 148) { src = Wh1; dst = wh1p; tile = b - 100; scale = s384; }
        else              { src = Wh2; dst = wh2p; tile = b - 148; scale = s16;  }
        const int kt0 = tile >> 2, nt0 = tile & 3;
        const int k0 = kt0 * 32, n0 = nt0 * 64;
#pragma unroll
        for (int i = 0; i < 8; ++i) {
            int p = tid + i * 256;
            int k = p >> 6, n = p & 63;
            T[k * 72 + n] = (__bf16)(src[(k0 + k) * 256 + n0 + n] * scale);
        }
        __syncthreads();
        const int ktl = tid >> 7, rem = tid & 127;
        const int n = rem >> 1, kh = rem & 1;
        bf16v8 v;
#pragma unroll
        for (int j = 0; j < 8; ++j)
            v[j] = T[(ktl * 16 + kh * 8 + j) * 72 + n];
        *(bf16v8*)(dst + (kt0 * 2 + ktl) * 4096 + (n0 + n) * 16 + kh * 8) = v;
        return;
    }
    if (b < 340) {      // ---- scalar fmt16: Wxl (8192 el), Whl (32768 el)
        int t = (b - 180) * 256 + tid;
        const float* src; __bf16* dst; int Nout; int idx; float scale;
        if (t < 8192)       { src = Wxl; dst = wxlp; Nout = 32;  idx = t;        scale = 1.0f; }
        else if (t < 40960) { src = Whl; dst = whlp; Nout = 128; idx = t - 8192; scale = s16;  }
        else return;
        int kt  = idx / (Nout * 32);
        int rem = idx - kt * Nout * 32;
        int n   = rem >> 5;
        int kk  = rem & 31;
        dst[idx] = (__bf16)(src[(kt * 32 + kk) * Nout + n] * scale);
        return;
    }
    if (b < 724) {      // ---- cvecg: per-receiver constant term of gemm1
        int r = b - 340;
        float a = 0.f;
#pragma unroll 4
        for (int k = 0; k < 128; ++k)
            a += nf[r * HH + k] * We1[(160 + k) * 256 + tid];
        cvecg[r * UU + tid] = a * s288;
        return;
    }
    if (b < 1108) {     // ---- svecg: per-sender constant term of gemm1
        int s = b - 724;
        float a = 0.f;
#pragma unroll 4
        for (int k = 0; k < 128; ++k)
            a += nf[s * HH + k] * We1[(32 + k) * 256 + tid];
        svecg[s * UU + tid] = a * s288;
        return;
    }
    // ---- zero accumulators: 33792 float4 = mi + shift ----
    ((f32x4*)zbase)[(b - 1108) * 256 + tid] = (f32x4){0.f, 0.f, 0.f, 0.f};
}

// ---- 32x256 GEMM (single m-tile): Y = silu(X @ Wp), 8 waves ---------------
template <int KT>
__device__ __forceinline__ void gemmS(const __bf16* X, int xs,
                                      const __bf16* __restrict__ P,
                                      __bf16* Y, int ys, int wave, int lane) {
    const int m  = lane & 31;
    const int kh = lane >> 5;
    f32x16 acc = {};
    const __bf16* xr = X + m * xs + kh * 8;
    const __bf16* pb = P + (wave * 32 + m) * 16 + kh * 8;
    bf16v8 b0 = *(const bf16v8*)(pb);
    bf16v8 b1 = (KT > 1) ? *(const bf16v8*)(pb + 4096) : b0;
#pragma unroll
    for (int kt = 0; kt < KT; ++kt) {
        bf16v8 a0 = *(const bf16v8*)(xr + kt * 16);
        bf16v8 bn = (kt + 2 < KT) ? *(const bf16v8*)(pb + (kt + 2) * 4096) : b0;
        acc = __builtin_amdgcn_mfma_f32_32x32x16_bf16(a0, b0, acc, 0, 0, 0);
        b0 = b1; b1 = bn;
    }
#pragma unroll
    for (int reg = 0; reg < 16; ++reg) {
        int row = (reg & 3) + 8 * (reg >> 2) + 4 * kh;
        Y[row * ys + wave * 32 + m] = (__bf16)fast_silu(acc[reg]);
    }
}

// ---- gemm1: Y = silu(len2 @ We1'[0:32] + svec[s] + cvec[r]), KT=2 ---------
__device__ __forceinline__ void gemm_e1(const __bf16* X,
                                        const __bf16* __restrict__ P,
                                        __bf16* Y, int wave, int lane,
                                        const float* __restrict__ cvec,
                                        const float* __restrict__ svecg,
                                        int r, int e0) {
    const int m   = lane & 31;
    const int kh  = lane >> 5;
    const int col = wave * 32 + m;
    float iv = cvec[col];
    f32x16 acc;
#pragma unroll
    for (int i = 0; i < 16; ++i) acc[i] = iv;
    const __bf16* xr = X + m * SS + kh * 8;
    const __bf16* pb = P + col * 16 + kh * 8;
    bf16v8 b0 = *(const bf16v8*)(pb);
    bf16v8 b1 = *(const bf16v8*)(pb + 4096);
    bf16v8 a0 = *(const bf16v8*)(xr);
    bf16v8 a1 = *(const bf16v8*)(xr + 16);
    acc = __builtin_amdgcn_mfma_f32_32x32x16_bf16(a0, b0, acc, 0, 0, 0);
    acc = __builtin_amdgcn_mfma_f32_32x32x16_bf16(a1, b1, acc, 0, 0, 0);
    const int sb = r + 1 + e0 + 4 * kh;           // sender base (< 768)
#pragma unroll
    for (int reg = 0; reg < 16; ++reg) {
        int ro  = (reg & 3) + 8 * (reg >> 2);     // row offset 0..27
        int row = ro + 4 * kh;
        int s   = sb + ro; if (s >= NN) s -= NN;
        float v = acc[reg] + svecg[s * UU + col]; // per-edge sender term (f32)
        Y[row * SS + col] = (__bf16)fast_silu(v);
    }
}

// --------------------------- fused edge kernel -----------------------------
__global__ __launch_bounds__(512, 8)
void edge_kernel(const float* __restrict__ nv, const float* __restrict__ nf,
                 const __bf16* __restrict__ we1p, const __bf16* __restrict__ we2p,
                 const __bf16* __restrict__ wx1p, const __bf16* __restrict__ wx2p,
                 const __bf16* __restrict__ wxlp, const float* __restrict__ bxl,
                 const float* __restrict__ winf, const float* __restrict__ cvecg,
                 const float* __restrict__ svecg,
                 float* __restrict__ shift, float* __restrict__ mi) {
    __shared__ __align__(16) __bf16 Ab[MM * SS];   // len2 -> m -> t2
    __shared__ __align__(16) __bf16 Bb[MM * SS];   // h1 -> t1 -> sred alias
    __shared__ float gateb[MM];

    const int tid  = threadIdx.x;
    const int wave = tid >> 6;
    const int lane = tid & 63;
    const int col  = lane & 15;
    const int q    = lane >> 4;
    const int r     = blockIdx.y;
    const int chunk = blockIdx.x;
    const int e0    = chunk * MM;

    // ---- stage: len2 (cols 0..31 only; nf[s] hoisted into svecg) ----
#pragma unroll
    for (int p = tid; p < MM * 32; p += 512) {     // 2 iters/thread
        int i = p >> 5, v = p & 31;
        int s = r + 1 + e0 + i; if (s >= NN) s -= NN;
        const float* pr = nv + (r * 32 + v) * 3;
        const float* ps = nv + (s * 32 + v) * 3;
        float d0 = pr[0] - ps[0];
        float d1 = pr[1] - ps[1];
        float d2 = pr[2] - ps[2];
        Ab[i * SS + v] = (__bf16)(d0 * d0 + d1 * d1 + d2 * d2);
    }
    __syncthreads();                                                   // B1

    // ---- h1 = silu(len2 @ We1'[0:32] + svec + cvec) : A -> B ----
    gemm_e1(Ab, we1p, Bb, wave, lane, cvecg + r * UU, svecg, r, e0);
    __syncthreads();                                                   // B2
    // ---- m = silu(h1 @ We2') : B -> A ----
    gemmS<16>(Bb, SS, we2p, Ab, SS, wave, lane);
    __syncthreads();                                                   // B3

    // ---- gate e = sigmoid(m @ Winf / 16); 16-lane shfl reduce ----
    {
        int i = tid >> 4, t = tid & 15, kq = t * 16;
        const __bf16* mrow = Ab + i * SS + kq;
        const float*  wrow = winf + kq;
        float g = 0.f;
#pragma unroll
        for (int k = 0; k < 16; ++k)
            g += (float)mrow[k] * wrow[k];
        g += __shfl_xor(g, 1);
        g += __shfl_xor(g, 2);
        g += __shfl_xor(g, 4);
        g += __shfl_xor(g, 8);
        if (t == 0)
            gateb[i] = (e0 + i == NN - 1) ? 0.f     // self-edge pad
                                          : fast_rcp(1.f + __expf(-g * 0.0625f));
    }
    __syncthreads();                                                   // B4

    // ---- m_i partials -> atomicAdd (waves 0-3; overlaps gemm3) ----
    if (tid < 256) {
        const __bf16* mcol = Ab + tid;
        float mp = 0.f;
#pragma unroll
        for (int i = 0; i < 32; ++i)
            mp += (float)mcol[i * SS] * gateb[i];
        atomicAdd(&mi[r * UU + tid], mp);
    }

    // ---- t1 = silu(m @ Wx1'): A -> B ; t2 = silu(t1 @ Wx2'): B -> A ----
    gemmS<16>(Ab, SS, wx1p, Bb, SS, wave, lane);
    __syncthreads();                                                   // B5
    gemmS<16>(Bb, SS, wx2p, Ab, SS, wave, lane);
    __syncthreads();                                                   // B6

    // ---- phi_x MFMA + shift in registers -> LDS partials (alias Bb) ----
    // wave w: mt=w&1 (16 edges), nt=(w>>1)&1 (16 v), ks=w>>2 (K half).
    // Partial-acc * f * d is linear in acc -> K halves sum independently.
    float* sred = (float*)Bb;                      // [32 v][16 g][3 c] = 6KB
    {
        int mt = wave & 1, nt = (wave >> 1) & 1, ks = wave >> 2;
        int v = nt * 16 + col;
        float bias = (ks == 0) ? bxl[v] : 0.f;
        f32x4 acc = {bias, bias, bias, bias};
        const __bf16* xr = Ab + (mt * 16 + col) * SS + ks * 128 + q * 8;
#pragma unroll
        for (int kt = 0; kt < 4; ++kt) {
            bf16v8 a = *(const bf16v8*)(xr + kt * 32);
            bf16v8 b = *(const bf16v8*)(wxlp + (ks * 4 + kt) * 1024 + v * 32 + q * 8);
            acc = __builtin_amdgcn_mfma_f32_16x16x32_bf16(a, b, acc, 0, 0, 0);
        }
        float r0 = nv[(r * 32 + v) * 3 + 0];
        float r1 = nv[(r * 32 + v) * 3 + 1];
        float r2 = nv[(r * 32 + v) * 3 + 2];
        float sp0 = 0.f, sp1 = 0.f, sp2 = 0.f;
#pragma unroll
        for (int i = 0; i < 4; ++i) {
            int e = mt * 16 + q * 4 + i;
            int s = r + 1 + e0 + e; if (s >= NN) s -= NN;
            const float* ps = nv + (s * 32 + v) * 3;
            float d0 = r0 - ps[0], d1 = r1 - ps[1], d2 = r2 - ps[2];
            float len = fast_sqrt(fmaxf(d0 * d0 + d1 * d1 + d2 * d2, 1e-20f));
            float w = acc[i] * fast_rcp(1.f + len);   // self-edge: d=0 -> 0
            sp0 += w * d0; sp1 += w * d1; sp2 += w * d2;
        }
        int g = (mt * 2 + ks) * 4 + q;
        sred[v * 48 + g * 3 + 0] = sp0;
        sred[v * 48 + g * 3 + 1] = sp1;
        sred[v * 48 + g * 3 + 2] = sp2;
    }
    __syncthreads();                                                   // B7

    // ---- reduce 16 groups -> one atomic per (v,c): 96 atomics/block ----
    if (tid < 96) {
        int v = tid / 3, c = tid - v * 3;
        float s = 0.f;
#pragma unroll
        for (int g = 0; g < 16; ++g)
            s += sred[v * 48 + g * 3 + c];
        atomicAdd(&shift[r * 96 + tid], s);
    }
}

// ---------------- node MLP (12 blocks x 32 rows) ---------------------------
__global__ __launch_bounds__(512)
void node_kernel(const float* __restrict__ nv, const float* __restrict__ nf,
                 const __bf16* __restrict__ wh1p, const __bf16* __restrict__ wh2p,
                 const __bf16* __restrict__ whlp,
                 const float* __restrict__ shift, const float* __restrict__ mi,
                 float* __restrict__ out) {
    __shared__ __align__(16) __bf16 xsb[32 * XS];   // [m_i | nf] 32x384
    __shared__ __align__(16) __bf16 h1b[32 * SS];
    __shared__ __align__(16) __bf16 h2b[32 * SS];
    const int tid  = threadIdx.x;
    const int wave = tid >> 6;
    const int lane = tid & 63;
    const int n0   = blockIdx.x * 32;

    // ---- stage xs = [m_i | nf]; vectors_out ----
#pragma unroll
    for (int p = tid; p < 32 * 256; p += 512) {
        int i = p >> 8, c = p & 255;
        xsb[i * XS + c] = (__bf16)mi[(n0 + i) * UU + c];
    }
#pragma unroll
    for (int p = tid; p < 32 * 128; p += 512) {
        int i = p >> 7, c = p & 127;
        xsb[i * XS + 256 + c] = (__bf16)nf[(n0 + i) * HH + c];
    }
#pragma unroll
    for (int p = tid; p < 32 * 96; p += 512) {
        int i = p / 96, j = p - i * 96;
        out[(n0 + i) * 96 + j] = nv[(n0 + i) * 96 + j]
                                 + shift[(n0 + i) * 96 + j] * (1.f / 383.f);
    }
    __syncthreads();

    // ---- h1 = silu(xs @ Wh1') ; h2 = silu(h1 @ Wh2') ----
    gemmS<24>(xsb, XS, wh1p, h1b, SS, wave, lane);
    __syncthreads();
    gemmS<16>(h1b, SS, wh2p, h2b, SS, wave, lane);
    __syncthreads();

    // ---- features_out = h2 @ Whl' + nf  (N=128, 16x16 MFMA, 8 n-tiles) ----
    {
        int col = lane & 15, q = lane >> 4;
        int n = wave * 16 + col;
#pragma unroll
        for (int mt = 0; mt < 2; ++mt) {
            f32x4 acc = {0.f, 0.f, 0.f, 0.f};
            const __bf16* xr = h2b + (mt * 16 + col) * SS + q * 8;
#pragma unroll
            for (int kt = 0; kt < 8; ++kt) {
                bf16v8 a = *(const bf16v8*)(xr + kt * 32);
                bf16v8 b = *(const bf16v8*)(whlp + kt * 4096 + n * 32 + q * 8);
                acc = __builtin_amdgcn_mfma_f32_16x16x32_bf16(a, b, acc, 0, 0, 0);
            }
#pragma unroll
            for (int i = 0; i < 4; ++i) {
                int row = n0 + mt * 16 + q * 4 + i;
                out[NN * 96 + row * HH + n] = acc[i] + nf[row * HH + n];
            }
        }
    }
}

// ------------------------------- launcher ----------------------------------
extern "C" void kernel_launch(void* const* d_in, const int* in_sizes, int n_in,
                              void* d_out, int out_size, void* d_ws, size_t ws_size,
                              hipStream_t stream) {
    const float* nv   = (const float*)d_in[0];
    const float* nf   = (const float*)d_in[1];
    const float* We1  = (const float*)d_in[2];
    const float* We2  = (const float*)d_in[3];
    const float* Wx1  = (const float*)d_in[4];
    const float* Wx2  = (const float*)d_in[5];
    const float* Wxl  = (const float*)d_in[6];
    const float* bxl  = (const float*)d_in[7];
    const float* Winf = (const float*)d_in[8];
    const float* Wh1  = (const float*)d_in[9];
    const float* Wh2  = (const float*)d_in[10];
    const float* Whl  = (const float*)d_in[11];
    float* out = (float*)d_out;

    char* ws = (char*)d_ws;
    float*  mi     = (float*)ws;                        // 384*256*4 = 393216
    float*  shift  = (float*)(ws + 393216);             // 384*96*4  = 147456
    float*  cvecg  = (float*)(ws + 540672);             // 393216
    float*  svecg  = (float*)(ws + 933888);             // 393216
    __bf16* we1p   = (__bf16*)(ws + 1327104);           // 16384 (k rows 0..31)
    __bf16* we2p   = (__bf16*)(ws + 1343488);           // 131072
    __bf16* wx1p   = (__bf16*)(ws + 1474560);           // 131072
    __bf16* wx2p   = (__bf16*)(ws + 1605632);           // 131072
    __bf16* wh1p   = (__bf16*)(ws + 1736704);           // 196608
    __bf16* wh2p   = (__bf16*)(ws + 1933312);           // 131072
    __bf16* wxlp   = (__bf16*)(ws + 2064384);           // 16384
    __bf16* whlp   = (__bf16*)(ws + 2080768);           // 65536

    repack_all<<<dim3(1240), 256, 0, stream>>>(We1, We2, Wx1, Wx2, Wh1, Wh2, Wxl, Whl,
                                               nf, we1p, we2p, wx1p, wx2p,
                                               wh1p, wh2p, wxlp, whlp, cvecg, svecg, mi);

    edge_kernel<<<dim3(NCHUNK, NN), 512, 0, stream>>>(nv, nf, we1p, we2p, wx1p, wx2p,
                                                      wxlp, bxl, Winf, cvecg, svecg,
                                                      shift, mi);
    node_kernel<<<dim3(12), 512, 0, stream>>>(nv, nf, wh1p, wh2p, whlp,
                                              shift, mi, out);
}

// Round 2
// 204.952 us; speedup vs baseline: 1.0309x; 1.0309x over previous
//
#include <hip/hip_runtime.h>
#include <hip/hip_bf16.h>

// EGCL (EGNN layer): N=384 nodes, V=32 vectors, H=128 feats, U=256 width.
// E = N*(N-1) = 147072 fully-connected edges. f32 in/out, bf16 MFMA compute.
// Edges grouped by RECEIVER r: segment sums are in-block reductions.
// R18 (R17 post-mortem): R17 doubled occupancy but doubled the B-operand L2
// stream (B bytes/block are M-invariant) -> hit the ~16.5 TB/s practical L2
// wall, flat at 125us. R18 gets BOTH: MM back to 64 (halves B-bytes/edge)
// AND 4 blocks/CU, via a SINGLE LDS ping-pong buffer: each gemm holds its
// 64x256 output in registers (32 bf16 = 16 packed VGPRs/lane) across one
// barrier, then writes back into the same buffer. LDS 67.5KB -> 34KB.
// Expected: L2 read ~2.1GB -> ~1.2GB, edge 125 -> ~90us.

#define NN 384
#define VV 32
#define HH 128
#define UU 256
#define MM 64            // edges per block
#define NCHUNK 6         // 6*64 = 384 = 383 edges + 1 pad
#define SS 264           // LDS row stride edge buffer (256-wide, +8 pad)
#define XS 392           // node xs row stride (384-wide, +8 pad)

typedef __bf16 bf16v8 __attribute__((ext_vector_type(8)));
typedef __bf16 bf16v4 __attribute__((ext_vector_type(4)));
typedef float  f32x4  __attribute__((ext_vector_type(4)));
typedef float  f32x16 __attribute__((ext_vector_type(16)));

__device__ __forceinline__ float fast_rcp(float x) { return __builtin_amdgcn_rcpf(x); }
__device__ __forceinline__ float fast_sqrt(float x) { return __builtin_amdgcn_sqrtf(x); }
__device__ __forceinline__ float fast_silu(float v) {
    return v * __builtin_amdgcn_rcpf(1.f + __expf(-v));
}
__device__ __forceinline__ unsigned pack_silu2(float a, float b) {
    unsigned short l = __builtin_bit_cast(unsigned short, (__bf16)fast_silu(a));
    unsigned short h = __builtin_bit_cast(unsigned short, (__bf16)fast_silu(b));
    return (unsigned)l | ((unsigned)h << 16);
}

// ---------------- repack + cvec/svec + accumulator zeroing -----------------
// blocks [0,180): fmt32 LDS-tiled transpose  P[kt][n][kk]=W[kt*16+kk][n]*s
//   We1 only needs k rows 0..31 (len2 block) -> 4 tiles.
// blocks [180,340): scalar fmt16 (Wxl, Whl)
// blocks [340,724): cvecg[r][n] = sum_k nf[r][k]*We1[160+k][n]*s288
// blocks [724,1108): svecg[s][n] = sum_k nf[s][k]*We1[ 32+k][n]*s288
// blocks [1108,1240): zero mi[384*256]+shift[384*96] (float4 stores)
__global__ __launch_bounds__(256)
void repack_all(const float* __restrict__ We1, const float* __restrict__ We2,
                const float* __restrict__ Wx1, const float* __restrict__ Wx2,
                const float* __restrict__ Wh1, const float* __restrict__ Wh2,
                const float* __restrict__ Wxl, const float* __restrict__ Whl,
                const float* __restrict__ nf,
                __bf16* __restrict__ we1p, __bf16* __restrict__ we2p,
                __bf16* __restrict__ wx1p, __bf16* __restrict__ wx2p,
                __bf16* __restrict__ wh1p, __bf16* __restrict__ wh2p,
                __bf16* __restrict__ wxlp, __bf16* __restrict__ whlp,
                float* __restrict__ cvecg, float* __restrict__ svecg,
                float* __restrict__ zbase) {
    const float s288 = 0.05892556509887896f;   // 1/sqrt(288)
    const float s384 = 0.05103103630798288f;   // 1/sqrt(384)
    const float s16  = 0.0625f;
    const int b   = blockIdx.x;
    const int tid = threadIdx.x;

    if (b < 180) {                               // ---- fmt32 transpose tiles
        __shared__ __bf16 T[32 * 72];
        const float* src; __bf16* dst; int tile; float scale;
        if (b < 4)        { src = We1; dst = we1p; tile = b;       scale = s288; }
        else if (b < 36)  { src = We2; dst = we2p; tile = b - 4;   scale = s16;  }
        else if (b < 68)  { src = Wx1; dst = wx1p; tile = b - 36;  scale = s16;  }
        else if (b < 100) { src = Wx2; dst = wx2p; tile = b - 68;  scale = s16;  }
        else if (b < 148) { src = Wh1; dst = wh1p; tile = b - 100; scale = s384; }
        else              { src = Wh2; dst = wh2p; tile = b - 148; scale = s16;  }
        const int kt0 = tile >> 2, nt0 = tile & 3;
        const int k0 = kt0 * 32, n0 = nt0 * 64;
#pragma unroll
        for (int i = 0; i < 8; ++i) {
            int p = tid + i * 256;
            int k = p >> 6, n = p & 63;
            T[k * 72 + n] = (__bf16)(src[(k0 + k) * 256 + n0 + n] * scale);
        }
        __syncthreads();
        const int ktl = tid >> 7, rem = tid & 127;
        const int n = rem >> 1, kh = rem & 1;
        bf16v8 v;
#pragma unroll
        for (int j = 0; j < 8; ++j)
            v[j] = T[(ktl * 16 + kh * 8 + j) * 72 + n];
        *(bf16v8*)(dst + (kt0 * 2 + ktl) * 4096 + (n0 + n) * 16 + kh * 8) = v;
        return;
    }
    if (b < 340) {      // ---- scalar fmt16: Wxl (8192 el), Whl (32768 el)
        int t = (b - 180) * 256 + tid;
        const float* src; __bf16* dst; int Nout; int idx; float scale;
        if (t < 8192)       { src = Wxl; dst = wxlp; Nout = 32;  idx = t;        scale = 1.0f; }
        else if (t < 40960) { src = Whl; dst = whlp; Nout = 128; idx = t - 8192; scale = s16;  }
        else return;
        int kt  = idx / (Nout * 32);
        int rem = idx - kt * Nout * 32;
        int n   = rem >> 5;
        int kk  = rem & 31;
        dst[idx] = (__bf16)(src[(kt * 32 + kk) * Nout + n] * scale);
        return;
    }
    if (b < 724) {      // ---- cvecg: per-receiver constant term of gemm1
        int r = b - 340;
        float a = 0.f;
#pragma unroll 4
        for (int k = 0; k < 128; ++k)
            a += nf[r * HH + k] * We1[(160 + k) * 256 + tid];
        cvecg[r * UU + tid] = a * s288;
        return;
    }
    if (b < 1108) {     // ---- svecg: per-sender constant term of gemm1
        int s = b - 724;
        float a = 0.f;
#pragma unroll 4
        for (int k = 0; k < 128; ++k)
            a += nf[s * HH + k] * We1[(32 + k) * 256 + tid];
        svecg[s * UU + tid] = a * s288;
        return;
    }
    // ---- zero accumulators: 33792 float4 = mi + shift ----
    ((f32x4*)zbase)[(b - 1108) * 256 + tid] = (f32x4){0.f, 0.f, 0.f, 0.f};
}

// ---- 64x256 GEMM read+compute: yv[16] = packed silu(X @ Wp), in regs ------
// Wave computes cols [wave*32, wave*32+32) for all 64 rows. Single-buffer:
// caller barriers, then writeY stores yv back into the same LDS buffer.
template <int KT>
__device__ __forceinline__ void gemmR(const __bf16* X, int xs,
                                      const __bf16* __restrict__ P,
                                      int wave, int lane, unsigned* yv) {
    const int m  = lane & 31;
    const int kh = lane >> 5;
    f32x16 acc0 = {}, acc1 = {};
    const __bf16* xr = X + m * xs + kh * 8;
    const __bf16* pb = P + (wave * 32 + m) * 16 + kh * 8;
#pragma unroll
    for (int kt = 0; kt < KT; ++kt) {
        bf16v8 a0 = *(const bf16v8*)(xr + kt * 16);
        bf16v8 a1 = *(const bf16v8*)(xr + 32 * xs + kt * 16);
        bf16v8 b  = *(const bf16v8*)(pb + kt * 4096);
        acc0 = __builtin_amdgcn_mfma_f32_32x32x16_bf16(a0, b, acc0, 0, 0, 0);
        acc1 = __builtin_amdgcn_mfma_f32_32x32x16_bf16(a1, b, acc1, 0, 0, 0);
    }
#pragma unroll
    for (int reg = 0; reg < 16; ++reg)
        yv[reg] = pack_silu2(acc0[reg], acc1[reg]);
}

__device__ __forceinline__ void writeY(__bf16* Y, int ys, int wave, int lane,
                                       const unsigned* yv) {
    const int m   = lane & 31;
    const int kh  = lane >> 5;
    const int col = wave * 32 + m;
#pragma unroll
    for (int reg = 0; reg < 16; ++reg) {
        int row = (reg & 3) + 8 * (reg >> 2) + 4 * kh;
        unsigned u = yv[reg];
        Y[row * ys + col]        = __builtin_bit_cast(__bf16, (unsigned short)(u & 0xffffu));
        Y[(32 + row) * ys + col] = __builtin_bit_cast(__bf16, (unsigned short)(u >> 16));
    }
}

// ---- gemm1: yv = silu(len2 @ We1'[0:32] + svec[s] + cvec[r]), KT=2 --------
__device__ __forceinline__ void gemm1R(const __bf16* X,
                                       const __bf16* __restrict__ P,
                                       int wave, int lane,
                                       const float* __restrict__ cvec,
                                       const float* __restrict__ svecg,
                                       int r, int e0, unsigned* yv) {
    const int m   = lane & 31;
    const int kh  = lane >> 5;
    const int col = wave * 32 + m;
    f32x16 acc0 = {}, acc1 = {};
    const __bf16* xr = X + m * SS + kh * 8;
    const __bf16* pb = P + col * 16 + kh * 8;
    bf16v8 b0 = *(const bf16v8*)(pb);
    bf16v8 b1 = *(const bf16v8*)(pb + 4096);
    bf16v8 a0 = *(const bf16v8*)(xr);
    bf16v8 a1 = *(const bf16v8*)(xr + 16);
    bf16v8 a2 = *(const bf16v8*)(xr + 32 * SS);
    bf16v8 a3 = *(const bf16v8*)(xr + 32 * SS + 16);
    acc0 = __builtin_amdgcn_mfma_f32_32x32x16_bf16(a0, b0, acc0, 0, 0, 0);
    acc0 = __builtin_amdgcn_mfma_f32_32x32x16_bf16(a1, b1, acc0, 0, 0, 0);
    acc1 = __builtin_amdgcn_mfma_f32_32x32x16_bf16(a2, b0, acc1, 0, 0, 0);
    acc1 = __builtin_amdgcn_mfma_f32_32x32x16_bf16(a3, b1, acc1, 0, 0, 0);
    float cv = cvec[col];
    const int sb = r + 1 + e0 + 4 * kh;           // sender base (< 768)
#pragma unroll
    for (int reg = 0; reg < 16; ++reg) {
        int ro = (reg & 3) + 8 * (reg >> 2);      // row offset 0..27
        int s0 = sb + ro;        if (s0 >= NN) s0 -= NN;
        int s1 = sb + ro + 32;   if (s1 >= NN) s1 -= NN;
        yv[reg] = pack_silu2(acc0[reg] + cv + svecg[s0 * UU + col],
                             acc1[reg] + cv + svecg[s1 * UU + col]);
    }
}

// --------------------------- fused edge kernel -----------------------------
__global__ __launch_bounds__(512, 8)
void edge_kernel(const float* __restrict__ nv, const float* __restrict__ nf,
                 const __bf16* __restrict__ we1p, const __bf16* __restrict__ we2p,
                 const __bf16* __restrict__ wx1p, const __bf16* __restrict__ wx2p,
                 const __bf16* __restrict__ wxlp, const float* __restrict__ bxl,
                 const float* __restrict__ winf, const float* __restrict__ cvecg,
                 const float* __restrict__ svecg,
                 float* __restrict__ shift, float* __restrict__ mi) {
    __shared__ __align__(16) __bf16 Ab[MM * SS];   // 33792 B, single buffer
    __shared__ float gateb[MM];

    const int tid  = threadIdx.x;
    const int wave = tid >> 6;
    const int lane = tid & 63;
    const int col  = lane & 15;
    const int q    = lane >> 4;
    const int r     = blockIdx.y;
    const int chunk = blockIdx.x;
    const int e0    = chunk * MM;

    unsigned yv[16];

    // ---- stage: len2 (cols 0..31; nf terms hoisted into svecg/cvecg) ----
#pragma unroll
    for (int p = tid; p < MM * 32; p += 512) {     // 4 iters/thread
        int i = p >> 5, v = p & 31;
        int s = r + 1 + e0 + i; if (s >= NN) s -= NN;
        const float* pr = nv + (r * 32 + v) * 3;
        const float* ps = nv + (s * 32 + v) * 3;
        float d0 = pr[0] - ps[0];
        float d1 = pr[1] - ps[1];
        float d2 = pr[2] - ps[2];
        Ab[i * SS + v] = (__bf16)(d0 * d0 + d1 * d1 + d2 * d2);
    }
    __syncthreads();                                                   // B1

    // ---- h1 = silu(len2 @ We1'[0:32] + svec + cvec) ----
    gemm1R(Ab, we1p, wave, lane, cvecg + r * UU, svecg, r, e0, yv);
    __syncthreads();                                                   // B2
    writeY(Ab, SS, wave, lane, yv);                // h1
    __syncthreads();                                                   // B3

    // ---- m = silu(h1 @ We2') ----
    gemmR<16>(Ab, SS, we2p, wave, lane, yv);
    __syncthreads();                                                   // B4
    writeY(Ab, SS, wave, lane, yv);                // m
    __syncthreads();                                                   // B5

    // ---- gate e = sigmoid(m @ Winf / 16); 8-lane shfl reduce ----
    {
        int i = tid >> 3, kq = (tid & 7) * 32;
        const __bf16* mrow = Ab + i * SS + kq;
        const float*  wrow = winf + kq;
        float g = 0.f;
#pragma unroll
        for (int k = 0; k < 32; ++k)
            g += (float)mrow[k] * wrow[k];
        g += __shfl_xor(g, 1);
        g += __shfl_xor(g, 2);
        g += __shfl_xor(g, 4);
        if ((tid & 7) == 0)
            gateb[i] = (e0 + i == NN - 1) ? 0.f     // self-edge pad
                                          : fast_rcp(1.f + __expf(-g * 0.0625f));
    }
    __syncthreads();                                                   // B6

    // ---- m_i partials -> atomicAdd (overlaps gemm3 reads; no barrier) ----
    {
        int c = tid & 255, ih = (tid >> 8) * 32;
        const __bf16* mcol = Ab + ih * SS + c;
        const float*  gp   = gateb + ih;
        float mp = 0.f;
#pragma unroll
        for (int i = 0; i < 32; ++i)
            mp += (float)mcol[i * SS] * gp[i];
        atomicAdd(&mi[r * UU + c], mp);
    }

    // ---- t1 = silu(m @ Wx1') ----
    gemmR<16>(Ab, SS, wx1p, wave, lane, yv);
    __syncthreads();                                                   // B7
    writeY(Ab, SS, wave, lane, yv);                // t1
    __syncthreads();                                                   // B8

    // ---- t2 = silu(t1 @ Wx2') ----
    gemmR<16>(Ab, SS, wx2p, wave, lane, yv);
    __syncthreads();                                                   // B9
    writeY(Ab, SS, wave, lane, yv);                // t2
    __syncthreads();                                                   // B10

    // ---- phi_x MFMA + shift in registers; sred aliases Ab after B11 ----
    // wave w: mt=w>>1 (16 edges), nt=w&1 (16 v). Full K (8 kt of 16x16x32).
    int mt = wave >> 1, nt = wave & 1;
    int v = nt * 16 + col;
    float sp0, sp1, sp2;
    {
        float bias = bxl[v];
        f32x4 acc = {bias, bias, bias, bias};
        const __bf16* xr = Ab + (mt * 16 + col) * SS + q * 8;
#pragma unroll
        for (int kt = 0; kt < 8; ++kt) {
            bf16v8 a = *(const bf16v8*)(xr + kt * 32);
            bf16v8 b = *(const bf16v8*)(wxlp + kt * 1024 + v * 32 + q * 8);
            acc = __builtin_amdgcn_mfma_f32_16x16x32_bf16(a, b, acc, 0, 0, 0);
        }
        float r0 = nv[(r * 32 + v) * 3 + 0];
        float r1 = nv[(r * 32 + v) * 3 + 1];
        float r2 = nv[(r * 32 + v) * 3 + 2];
        sp0 = 0.f; sp1 = 0.f; sp2 = 0.f;
#pragma unroll
        for (int i = 0; i < 4; ++i) {
            int e = mt * 16 + q * 4 + i;
            int s = r + 1 + e0 + e; if (s >= NN) s -= NN;
            const float* ps = nv + (s * 32 + v) * 3;
            float d0 = r0 - ps[0], d1 = r1 - ps[1], d2 = r2 - ps[2];
            float len = fast_sqrt(fmaxf(d0 * d0 + d1 * d1 + d2 * d2, 1e-20f));
            float w = acc[i] * fast_rcp(1.f + len);   // self-edge: d=0 -> 0
            sp0 += w * d0; sp1 += w * d1; sp2 += w * d2;
        }
    }
    __syncthreads();                                                   // B11
    float* sred = (float*)Ab;                      // [32 v][16 g][3 c] = 6KB
    {
        int g = mt * 4 + q;
        sred[v * 48 + g * 3 + 0] = sp0;
        sred[v * 48 + g * 3 + 1] = sp1;
        sred[v * 48 + g * 3 + 2] = sp2;
    }
    __syncthreads();                                                   // B12

    // ---- reduce 16 groups -> one atomic per (v,c): 96 atomics/block ----
    if (tid < 96) {
        int vv = tid / 3, c = tid - vv * 3;
        float s = 0.f;
#pragma unroll
        for (int g = 0; g < 16; ++g)
            s += sred[vv * 48 + g * 3 + c];
        atomicAdd(&shift[r * 96 + tid], s);
    }
}

// ---------------- node MLP (12 blocks x 32 rows) ---------------------------
__global__ __launch_bounds__(512)
void node_kernel(const float* __restrict__ nv, const float* __restrict__ nf,
                 const __bf16* __restrict__ wh1p, const __bf16* __restrict__ wh2p,
                 const __bf16* __restrict__ whlp,
                 const float* __restrict__ shift, const float* __restrict__ mi,
                 float* __restrict__ out) {
    __shared__ __align__(16) __bf16 xsb[32 * XS];   // [m_i | nf] 32x384
    __shared__ __align__(16) __bf16 h1b[32 * SS];
    __shared__ __align__(16) __bf16 h2b[32 * SS];
    const int tid  = threadIdx.x;
    const int wave = tid >> 6;
    const int lane = tid & 63;
    const int n0   = blockIdx.x * 32;

    // ---- stage xs = [m_i | nf]; vectors_out ----
#pragma unroll
    for (int p = tid; p < 32 * 256; p += 512) {
        int i = p >> 8, c = p & 255;
        xsb[i * XS + c] = (__bf16)mi[(n0 + i) * UU + c];
    }
#pragma unroll
    for (int p = tid; p < 32 * 128; p += 512) {
        int i = p >> 7, c = p & 127;
        xsb[i * XS + 256 + c] = (__bf16)nf[(n0 + i) * HH + c];
    }
#pragma unroll
    for (int p = tid; p < 32 * 96; p += 512) {
        int i = p / 96, j = p - i * 96;
        out[(n0 + i) * 96 + j] = nv[(n0 + i) * 96 + j]
                                 + shift[(n0 + i) * 96 + j] * (1.f / 383.f);
    }
    __syncthreads();

    // ---- h1 = silu(xs @ Wh1') ; h2 = silu(h1 @ Wh2') ----
    {
        const int m  = lane & 31;
        const int kh = lane >> 5;
        f32x16 acc = {};
        const __bf16* xr = xsb + m * XS + kh * 8;
        const __bf16* pb = wh1p + (wave * 32 + m) * 16 + kh * 8;
#pragma unroll
        for (int kt = 0; kt < 24; ++kt) {
            bf16v8 a0 = *(const bf16v8*)(xr + kt * 16);
            bf16v8 b  = *(const bf16v8*)(pb + kt * 4096);
            acc = __builtin_amdgcn_mfma_f32_32x32x16_bf16(a0, b, acc, 0, 0, 0);
        }
#pragma unroll
        for (int reg = 0; reg < 16; ++reg) {
            int row = (reg & 3) + 8 * (reg >> 2) + 4 * kh;
            h1b[row * SS + wave * 32 + m] = (__bf16)fast_silu(acc[reg]);
        }
    }
    __syncthreads();
    {
        const int m  = lane & 31;
        const int kh = lane >> 5;
        f32x16 acc = {};
        const __bf16* xr = h1b + m * SS + kh * 8;
        const __bf16* pb = wh2p + (wave * 32 + m) * 16 + kh * 8;
#pragma unroll
        for (int kt = 0; kt < 16; ++kt) {
            bf16v8 a0 = *(const bf16v8*)(xr + kt * 16);
            bf16v8 b  = *(const bf16v8*)(pb + kt * 4096);
            acc = __builtin_amdgcn_mfma_f32_32x32x16_bf16(a0, b, acc, 0, 0, 0);
        }
#pragma unroll
        for (int reg = 0; reg < 16; ++reg) {
            int row = (reg & 3) + 8 * (reg >> 2) + 4 * kh;
            h2b[row * SS + wave * 32 + m] = (__bf16)fast_silu(acc[reg]);
        }
    }
    __syncthreads();

    // ---- features_out = h2 @ Whl' + nf  (N=128, 16x16 MFMA, 8 n-tiles) ----
    {
        int col = lane & 15, q = lane >> 4;
        int n = wave * 16 + col;
#pragma unroll
        for (int mt = 0; mt < 2; ++mt) {
            f32x4 acc = {0.f, 0.f, 0.f, 0.f};
            const __bf16* xr = h2b + (mt * 16 + col) * SS + q * 8;
#pragma unroll
            for (int kt = 0; kt < 8; ++kt) {
                bf16v8 a = *(const bf16v8*)(xr + kt * 32);
                bf16v8 b = *(const bf16v8*)(whlp + kt * 4096 + n * 32 + q * 8);
                acc = __builtin_amdgcn_mfma_f32_16x16x32_bf16(a, b, acc, 0, 0, 0);
            }
#pragma unroll
            for (int i = 0; i < 4; ++i) {
                int row = n0 + mt * 16 + q * 4 + i;
                out[NN * 96 + row * HH + n] = acc[i] + nf[row * HH + n];
            }
        }
    }
}

// ------------------------------- launcher ----------------------------------
extern "C" void kernel_launch(void* const* d_in, const int* in_sizes, int n_in,
                              void* d_out, int out_size, void* d_ws, size_t ws_size,
                              hipStream_t stream) {
    const float* nv   = (const float*)d_in[0];
    const float* nf   = (const float*)d_in[1];
    const float* We1  = (const float*)d_in[2];
    const float* We2  = (const float*)d_in[3];
    const float* Wx1  = (const float*)d_in[4];
    const float* Wx2  = (const float*)d_in[5];
    const float* Wxl  = (const float*)d_in[6];
    const float* bxl  = (const float*)d_in[7];
    const float* Winf = (const float*)d_in[8];
    const float* Wh1  = (const float*)d_in[9];
    const float* Wh2  = (const float*)d_in[10];
    const float* Whl  = (const float*)d_in[11];
    float* out = (float*)d_out;

    char* ws = (char*)d_ws;
    float*  mi     = (float*)ws;                        // 384*256*4 = 393216
    float*  shift  = (float*)(ws + 393216);             // 384*96*4  = 147456
    float*  cvecg  = (float*)(ws + 540672);             // 393216
    float*  svecg  = (float*)(ws + 933888);             // 393216
    __bf16* we1p   = (__bf16*)(ws + 1327104);           // 16384 (k rows 0..31)
    __bf16* we2p   = (__bf16*)(ws + 1343488);           // 131072
    __bf16* wx1p   = (__bf16*)(ws + 1474560);           // 131072
    __bf16* wx2p   = (__bf16*)(ws + 1605632);           // 131072
    __bf16* wh1p   = (__bf16*)(ws + 1736704);           // 196608
    __bf16* wh2p   = (__bf16*)(ws + 1933312);           // 131072
    __bf16* wxlp   = (__bf16*)(ws + 2064384);           // 16384
    __bf16* whlp   = (__bf16*)(ws + 2080768);           // 65536

    repack_all<<<dim3(1240), 256, 0, stream>>>(We1, We2, Wx1, Wx2, Wh1, Wh2, Wxl, Whl,
                                               nf, we1p, we2p, wx1p, wx2p,
                                               wh1p, wh2p, wxlp, whlp, cvecg, svecg, mi);

    edge_kernel<<<dim3(NCHUNK, NN), 512, 0, stream>>>(nv, nf, we1p, we2p, wx1p, wx2p,
                                                      wxlp, bxl, Winf, cvecg, svecg,
                                                      shift, mi);
    node_kernel<<<dim3(12), 512, 0, stream>>>(nv, nf, wh1p, wh2p, whlp,
                                              shift, mi, out);
}

// Round 3
// 200.653 us; speedup vs baseline: 1.0530x; 1.0214x over previous
//
#include <hip/hip_runtime.h>
#include <hip/hip_bf16.h>

// EGCL (EGNN layer): N=384 nodes, V=32 vectors, H=128 feats, U=256 width.
// E = N*(N-1) = 147072 fully-connected edges. f32 in/out, bf16 MFMA compute.
// Edges grouped by RECEIVER r: segment sums are in-block reductions.
// R19 (R16/R17/R18 post-mortem): time invariant to occupancy (40->77%) and
// L2 weight stream (1.1->2.1GB) => instruction-stream bound (LDS pipe +
// VALU). Fix: SWAP MFMA OPERANDS in all edge gemms (compute Y^T = W'.X^T).
// Read addresses are unchanged (A/B frags mirror); D-layout flips so lanes
// hold one EDGE x 16 quad-contiguous features:
//  - writeY: 8x ds_write_b64 (was 32x ds_write_b16)
//  - gemm1 epilogue: svec/cvec become float4 loads (sender is per-lane const)
//  - gate: 4x b128 row reads (was 32x u16)
//  - mi: row-wise b128 + shfl_xor(32) + 4KB LDS partials; 256 atomics/block
// LDS-pipe cycles/block ~19.5K -> ~13.5K. Weights/repack/node unchanged.

#define NN 384
#define VV 32
#define HH 128
#define UU 256
#define MM 64            // edges per block
#define NCHUNK 6         // 6*64 = 384 = 383 edges + 1 pad
#define SS 264           // LDS row stride edge buffer (256-wide, +8 pad)
#define XS 392           // node xs row stride (384-wide, +8 pad)

typedef __bf16 bf16v8 __attribute__((ext_vector_type(8)));
typedef __bf16 bf16v4 __attribute__((ext_vector_type(4)));
typedef float  f32x4  __attribute__((ext_vector_type(4)));
typedef float  f32x16 __attribute__((ext_vector_type(16)));
typedef unsigned u32x2 __attribute__((ext_vector_type(2)));

__device__ __forceinline__ float fast_rcp(float x) { return __builtin_amdgcn_rcpf(x); }
__device__ __forceinline__ float fast_sqrt(float x) { return __builtin_amdgcn_sqrtf(x); }
__device__ __forceinline__ float fast_silu(float v) {
    return v * __builtin_amdgcn_rcpf(1.f + __expf(-v));
}
__device__ __forceinline__ unsigned pack_silu2(float a, float b) {
    unsigned short l = __builtin_bit_cast(unsigned short, (__bf16)fast_silu(a));
    unsigned short h = __builtin_bit_cast(unsigned short, (__bf16)fast_silu(b));
    return (unsigned)l | ((unsigned)h << 16);
}
__device__ __forceinline__ unsigned pack_bf2(float a, float b) {
    unsigned short l = __builtin_bit_cast(unsigned short, (__bf16)a);
    unsigned short h = __builtin_bit_cast(unsigned short, (__bf16)b);
    return (unsigned)l | ((unsigned)h << 16);
}

// ---------------- repack + cvec/svec + accumulator zeroing -----------------
// blocks [0,180): fmt32 LDS-tiled transpose  P[kt][n][kk]=W[kt*16+kk][n]*s
//   We1 only needs k rows 0..31 (len2 block) -> 4 tiles.
// blocks [180,340): scalar fmt16 (Wxl, Whl)
// blocks [340,724): cvecg[r][n] = sum_k nf[r][k]*We1[160+k][n]*s288
// blocks [724,1108): svecg[s][n] = sum_k nf[s][k]*We1[ 32+k][n]*s288
// blocks [1108,1240): zero mi[384*256]+shift[384*96] (float4 stores)
__global__ __launch_bounds__(256)
void repack_all(const float* __restrict__ We1, const float* __restrict__ We2,
                const float* __restrict__ Wx1, const float* __restrict__ Wx2,
                const float* __restrict__ Wh1, const float* __restrict__ Wh2,
                const float* __restrict__ Wxl, const float* __restrict__ Whl,
                const float* __restrict__ nf,
                __bf16* __restrict__ we1p, __bf16* __restrict__ we2p,
                __bf16* __restrict__ wx1p, __bf16* __restrict__ wx2p,
                __bf16* __restrict__ wh1p, __bf16* __restrict__ wh2p,
                __bf16* __restrict__ wxlp, __bf16* __restrict__ whlp,
                float* __restrict__ cvecg, float* __restrict__ svecg,
                float* __restrict__ zbase) {
    const float s288 = 0.05892556509887896f;   // 1/sqrt(288)
    const float s384 = 0.05103103630798288f;   // 1/sqrt(384)
    const float s16  = 0.0625f;
    const int b   = blockIdx.x;
    const int tid = threadIdx.x;

    if (b < 180) {                               // ---- fmt32 transpose tiles
        __shared__ __bf16 T[32 * 72];
        const float* src; __bf16* dst; int tile; float scale;
        if (b < 4)        { src = We1; dst = we1p; tile = b;       scale = s288; }
        else if (b < 36)  { src = We2; dst = we2p; tile = b - 4;   scale = s16;  }
        else if (b < 68)  { src = Wx1; dst = wx1p; tile = b - 36;  scale = s16;  }
        else if (b < 100) { src = Wx2; dst = wx2p; tile = b - 68;  scale = s16;  }
        else if (b < 148) { src = Wh1; dst = wh1p; tile = b - 100; scale = s384; }
        else              { src = Wh2; dst = wh2p; tile = b - 148; scale = s16;  }
        const int kt0 = tile >> 2, nt0 = tile & 3;
        const int k0 = kt0 * 32, n0 = nt0 * 64;
#pragma unroll
        for (int i = 0; i < 8; ++i) {
            int p = tid + i * 256;
            int k = p >> 6, n = p & 63;
            T[k * 72 + n] = (__bf16)(src[(k0 + k) * 256 + n0 + n] * scale);
        }
        __syncthreads();
        const int ktl = tid >> 7, rem = tid & 127;
        const int n = rem >> 1, kh = rem & 1;
        bf16v8 v;
#pragma unroll
        for (int j = 0; j < 8; ++j)
            v[j] = T[(ktl * 16 + kh * 8 + j) * 72 + n];
        *(bf16v8*)(dst + (kt0 * 2 + ktl) * 4096 + (n0 + n) * 16 + kh * 8) = v;
        return;
    }
    if (b < 340) {      // ---- scalar fmt16: Wxl (8192 el), Whl (32768 el)
        int t = (b - 180) * 256 + tid;
        const float* src; __bf16* dst; int Nout; int idx; float scale;
        if (t < 8192)       { src = Wxl; dst = wxlp; Nout = 32;  idx = t;        scale = 1.0f; }
        else if (t < 40960) { src = Whl; dst = whlp; Nout = 128; idx = t - 8192; scale = s16;  }
        else return;
        int kt  = idx / (Nout * 32);
        int rem = idx - kt * Nout * 32;
        int n   = rem >> 5;
        int kk  = rem & 31;
        dst[idx] = (__bf16)(src[(kt * 32 + kk) * Nout + n] * scale);
        return;
    }
    if (b < 724) {      // ---- cvecg: per-receiver constant term of gemm1
        int r = b - 340;
        float a = 0.f;
#pragma unroll 4
        for (int k = 0; k < 128; ++k)
            a += nf[r * HH + k] * We1[(160 + k) * 256 + tid];
        cvecg[r * UU + tid] = a * s288;
        return;
    }
    if (b < 1108) {     // ---- svecg: per-sender constant term of gemm1
        int s = b - 724;
        float a = 0.f;
#pragma unroll 4
        for (int k = 0; k < 128; ++k)
            a += nf[s * HH + k] * We1[(32 + k) * 256 + tid];
        svecg[s * UU + tid] = a * s288;
        return;
    }
    // ---- zero accumulators: 33792 float4 = mi + shift ----
    ((f32x4*)zbase)[(b - 1108) * 256 + tid] = (f32x4){0.f, 0.f, 0.f, 0.f};
}

// ---- swapped 64x256 GEMM: yv = packed silu((X @ Wp)^T), all in regs -------
// A = weights (rows = features n), B = X^T (cols = edges). Read addresses
// identical to the non-swapped form; D: lane holds edge = lane&31 (acc0) /
// +32 (acc1), features n = wave*32 + 8g + 4kh + t (quad-contiguous).
template <int KT>
__device__ __forceinline__ void gemmR(const __bf16* X, int xs,
                                      const __bf16* __restrict__ P,
                                      int wave, int lane, unsigned* yv) {
    const int idx = lane & 31;
    const int kh  = lane >> 5;
    f32x16 acc0 = {}, acc1 = {};
    const __bf16* xb = X + idx * xs + kh * 8;
    const __bf16* wr = P + (wave * 32 + idx) * 16 + kh * 8;
#pragma unroll
    for (int kt = 0; kt < KT; ++kt) {
        bf16v8 w  = *(const bf16v8*)(wr + kt * 4096);
        bf16v8 x0 = *(const bf16v8*)(xb + kt * 16);
        bf16v8 x1 = *(const bf16v8*)(xb + 32 * xs + kt * 16);
        acc0 = __builtin_amdgcn_mfma_f32_32x32x16_bf16(w, x0, acc0, 0, 0, 0);
        acc1 = __builtin_amdgcn_mfma_f32_32x32x16_bf16(w, x1, acc1, 0, 0, 0);
    }
#pragma unroll
    for (int g = 0; g < 4; ++g) {
        yv[2 * g]       = pack_silu2(acc0[4 * g + 0], acc0[4 * g + 1]);
        yv[2 * g + 1]   = pack_silu2(acc0[4 * g + 2], acc0[4 * g + 3]);
        yv[8 + 2 * g]   = pack_silu2(acc1[4 * g + 0], acc1[4 * g + 1]);
        yv[9 + 2 * g]   = pack_silu2(acc1[4 * g + 2], acc1[4 * g + 3]);
    }
}

// writeback: lane's edge row, 4 quads x b64 per acc tile
__device__ __forceinline__ void writeY(__bf16* Y, int ys, int wave, int lane,
                                       const unsigned* yv) {
    const int e  = lane & 31;
    const int kh = lane >> 5;
    __bf16* p0 = Y + e * ys + wave * 32 + 4 * kh;
#pragma unroll
    for (int g = 0; g < 4; ++g) {
        u32x2 a = { yv[2 * g], yv[2 * g + 1] };
        u32x2 b = { yv[8 + 2 * g], yv[9 + 2 * g] };
        *(u32x2*)(p0 + g * 8) = a;
        *(u32x2*)(p0 + 32 * ys + g * 8) = b;
    }
}

// ---- gemm1 swapped: yv = silu(len2 @ We1'[0:32] + svec[s] + cvec[r]) ------
// Sender is per-lane constant -> svec/cvec add via float4 loads.
__device__ __forceinline__ void gemm1R(const __bf16* X,
                                       const __bf16* __restrict__ P,
                                       int wave, int lane,
                                       const float* __restrict__ cvec,
                                       const float* __restrict__ svecg,
                                       int r, int e0, unsigned* yv) {
    const int idx = lane & 31;
    const int kh  = lane >> 5;
    f32x16 acc0 = {}, acc1 = {};
    const __bf16* xb = X + idx * SS + kh * 8;
    const __bf16* wr = P + (wave * 32 + idx) * 16 + kh * 8;
    bf16v8 w0  = *(const bf16v8*)(wr);
    bf16v8 w1  = *(const bf16v8*)(wr + 4096);
    bf16v8 x00 = *(const bf16v8*)(xb);
    bf16v8 x01 = *(const bf16v8*)(xb + 16);
    bf16v8 x10 = *(const bf16v8*)(xb + 32 * SS);
    bf16v8 x11 = *(const bf16v8*)(xb + 32 * SS + 16);
    acc0 = __builtin_amdgcn_mfma_f32_32x32x16_bf16(w0, x00, acc0, 0, 0, 0);
    acc0 = __builtin_amdgcn_mfma_f32_32x32x16_bf16(w1, x01, acc0, 0, 0, 0);
    acc1 = __builtin_amdgcn_mfma_f32_32x32x16_bf16(w0, x10, acc1, 0, 0, 0);
    acc1 = __builtin_amdgcn_mfma_f32_32x32x16_bf16(w1, x11, acc1, 0, 0, 0);
    int s0 = r + 1 + e0 + idx; if (s0 >= NN) s0 -= NN;
    int s1 = s0 + 32;          if (s1 >= NN) s1 -= NN;
    const int nb = wave * 32 + 4 * kh;
    const float* cp  = cvec + nb;
    const float* sp0 = svecg + s0 * UU + nb;
    const float* sp1 = svecg + s1 * UU + nb;
#pragma unroll
    for (int g = 0; g < 4; ++g) {
        f32x4 c = *(const f32x4*)(cp + 8 * g);
        f32x4 a = *(const f32x4*)(sp0 + 8 * g);
        f32x4 b = *(const f32x4*)(sp1 + 8 * g);
        yv[2 * g]     = pack_silu2(acc0[4 * g + 0] + c[0] + a[0],
                                   acc0[4 * g + 1] + c[1] + a[1]);
        yv[2 * g + 1] = pack_silu2(acc0[4 * g + 2] + c[2] + a[2],
                                   acc0[4 * g + 3] + c[3] + a[3]);
        yv[8 + 2 * g] = pack_silu2(acc1[4 * g + 0] + c[0] + b[0],
                                   acc1[4 * g + 1] + c[1] + b[1]);
        yv[9 + 2 * g] = pack_silu2(acc1[4 * g + 2] + c[2] + b[2],
                                   acc1[4 * g + 3] + c[3] + b[3]);
    }
}

// --------------------------- fused edge kernel -----------------------------
__global__ __launch_bounds__(512, 8)
void edge_kernel(const float* __restrict__ nv, const float* __restrict__ nf,
                 const __bf16* __restrict__ we1p, const __bf16* __restrict__ we2p,
                 const __bf16* __restrict__ wx1p, const __bf16* __restrict__ wx2p,
                 const __bf16* __restrict__ wxlp, const float* __restrict__ bxl,
                 const float* __restrict__ winf, const float* __restrict__ cvecg,
                 const float* __restrict__ svecg,
                 float* __restrict__ shift, float* __restrict__ mi) {
    __shared__ __align__(16) __bf16 Ab[MM * SS];   // 33792 B, single buffer
    __shared__ __align__(16) float mired[4 * 256]; // mi wave-partials, 4 KB
    __shared__ float gateb[MM];

    const int tid  = threadIdx.x;
    const int wave = tid >> 6;
    const int lane = tid & 63;
    const int col  = lane & 15;
    const int q    = lane >> 4;
    const int r     = blockIdx.y;
    const int chunk = blockIdx.x;
    const int e0    = chunk * MM;

    unsigned yv[16];

    // ---- stage: len2 (cols 0..31; nf terms hoisted into svecg/cvecg) ----
#pragma unroll
    for (int p = tid; p < MM * 16; p += 512) {     // 2 iters, packed b32
        int i = p >> 4, v = (p & 15) << 1;
        int s = r + 1 + e0 + i; if (s >= NN) s -= NN;
        const float* pr = nv + (r * 32 + v) * 3;
        const float* ps = nv + (s * 32 + v) * 3;
        float a0 = pr[0] - ps[0], a1 = pr[1] - ps[1], a2 = pr[2] - ps[2];
        float b0 = pr[3] - ps[3], b1 = pr[4] - ps[4], b2 = pr[5] - ps[5];
        *(unsigned*)&Ab[i * SS + v] = pack_bf2(a0 * a0 + a1 * a1 + a2 * a2,
                                               b0 * b0 + b1 * b1 + b2 * b2);
    }
    __syncthreads();                                                   // B1

    // ---- h1 = silu(len2 @ We1'[0:32] + svec + cvec) ----
    gemm1R(Ab, we1p, wave, lane, cvecg + r * UU, svecg, r, e0, yv);
    __syncthreads();                                                   // B2
    writeY(Ab, SS, wave, lane, yv);                // h1
    __syncthreads();                                                   // B3

    // ---- m = silu(h1 @ We2') ----
    gemmR<16>(Ab, SS, we2p, wave, lane, yv);
    __syncthreads();                                                   // B4
    writeY(Ab, SS, wave, lane, yv);                // m
    __syncthreads();                                                   // B5

    // ---- gate e = sigmoid(m @ Winf / 16); vector reads, 8-lane reduce ----
    {
        int i = tid >> 3, kq = (tid & 7) * 32;
        const __bf16* mrow = Ab + i * SS + kq;
        const f32x4* wv = (const f32x4*)(winf + kq);
        float g = 0.f;
#pragma unroll
        for (int t = 0; t < 4; ++t) {
            bf16v8 v = *(const bf16v8*)(mrow + t * 8);
            f32x4 wa = wv[2 * t], wb = wv[2 * t + 1];
            g += (float)v[0] * wa[0] + (float)v[1] * wa[1] +
                 (float)v[2] * wa[2] + (float)v[3] * wa[3] +
                 (float)v[4] * wb[0] + (float)v[5] * wb[1] +
                 (float)v[6] * wb[2] + (float)v[7] * wb[3];
        }
        g += __shfl_xor(g, 1);
        g += __shfl_xor(g, 2);
        g += __shfl_xor(g, 4);
        if ((tid & 7) == 0)
            gateb[i] = (e0 + i == NN - 1) ? 0.f     // self-edge pad
                                          : fast_rcp(1.f + __expf(-g * 0.0625f));
    }
    __syncthreads();                                                   // B6

    // ---- mi partials: waves 0-3, row-wise b128 reads; overlaps gemm3 ----
    // thread (w, egh, oct): edges (w*2+egh)*8..+8, cols oct*8..+8.
    if (tid < 256) {
        const int w   = tid >> 6;
        const int oct = lane & 31;
        const int egh = lane >> 5;
        const int eg  = w * 2 + egh;
        const __bf16* mp = Ab + (eg * 8) * SS + oct * 8;
        f32x4 g0 = *(const f32x4*)(gateb + eg * 8);
        f32x4 g1 = *(const f32x4*)(gateb + eg * 8 + 4);
        float p[8] = {0.f, 0.f, 0.f, 0.f, 0.f, 0.f, 0.f, 0.f};
#pragma unroll
        for (int i = 0; i < 8; ++i) {
            bf16v8 v = *(const bf16v8*)(mp + i * SS);
            float gv = (i < 4) ? g0[i] : g1[i - 4];
#pragma unroll
            for (int j = 0; j < 8; ++j)
                p[j] += (float)v[j] * gv;
        }
#pragma unroll
        for (int j = 0; j < 8; ++j)                // combine eg pair (xor 32)
            p[j] += __shfl_xor(p[j], 32);
        if (egh == 0) {
            f32x4 a = {p[0], p[1], p[2], p[3]};
            f32x4 b = {p[4], p[5], p[6], p[7]};
            *(f32x4*)(mired + w * 256 + oct * 8)     = a;
            *(f32x4*)(mired + w * 256 + oct * 8 + 4) = b;
        }
    }

    // ---- t1 = silu(m @ Wx1') ----
    gemmR<16>(Ab, SS, wx1p, wave, lane, yv);
    __syncthreads();                                                   // B7
    writeY(Ab, SS, wave, lane, yv);                // t1
    // mi finalize: reduce 4 wave-partials -> one atomic per col
    if (tid < 256) {
        float s = mired[tid] + mired[256 + tid] + mired[512 + tid] + mired[768 + tid];
        atomicAdd(&mi[r * UU + tid], s);
    }
    __syncthreads();                                                   // B8

    // ---- t2 = silu(t1 @ Wx2') ----
    gemmR<16>(Ab, SS, wx2p, wave, lane, yv);
    __syncthreads();                                                   // B9
    writeY(Ab, SS, wave, lane, yv);                // t2
    __syncthreads();                                                   // B10

    // ---- phi_x MFMA + shift in registers; sred aliases Ab after B11 ----
    // wave w: mt=w>>1 (16 edges), nt=w&1 (16 v). Full K (8 kt of 16x16x32).
    int mt = wave >> 1, nt = wave & 1;
    int v = nt * 16 + col;
    float sp0, sp1, sp2;
    {
        float bias = bxl[v];
        f32x4 acc = {bias, bias, bias, bias};
        const __bf16* xr = Ab + (mt * 16 + col) * SS + q * 8;
#pragma unroll
        for (int kt = 0; kt < 8; ++kt) {
            bf16v8 a = *(const bf16v8*)(xr + kt * 32);
            bf16v8 b = *(const bf16v8*)(wxlp + kt * 1024 + v * 32 + q * 8);
            acc = __builtin_amdgcn_mfma_f32_16x16x32_bf16(a, b, acc, 0, 0, 0);
        }
        float r0 = nv[(r * 32 + v) * 3 + 0];
        float r1 = nv[(r * 32 + v) * 3 + 1];
        float r2 = nv[(r * 32 + v) * 3 + 2];
        sp0 = 0.f; sp1 = 0.f; sp2 = 0.f;
#pragma unroll
        for (int i = 0; i < 4; ++i) {
            int e = mt * 16 + q * 4 + i;
            int s = r + 1 + e0 + e; if (s >= NN) s -= NN;
            const float* ps = nv + (s * 32 + v) * 3;
            float d0 = r0 - ps[0], d1 = r1 - ps[1], d2 = r2 - ps[2];
            float len = fast_sqrt(fmaxf(d0 * d0 + d1 * d1 + d2 * d2, 1e-20f));
            float w = acc[i] * fast_rcp(1.f + len);   // self-edge: d=0 -> 0
            sp0 += w * d0; sp1 += w * d1; sp2 += w * d2;
        }
    }
    __syncthreads();                                                   // B11
    float* sred = (float*)Ab;                      // [32 v][16 g][3 c] = 6KB
    {
        int g = mt * 4 + q;
        sred[v * 48 + g * 3 + 0] = sp0;
        sred[v * 48 + g * 3 + 1] = sp1;
        sred[v * 48 + g * 3 + 2] = sp2;
    }
    __syncthreads();                                                   // B12

    // ---- reduce 16 groups -> one atomic per (v,c): 96 atomics/block ----
    if (tid < 96) {
        int vv = tid / 3, c = tid - vv * 3;
        float s = 0.f;
#pragma unroll
        for (int g = 0; g < 16; ++g)
            s += sred[vv * 48 + g * 3 + c];
        atomicAdd(&shift[r * 96 + tid], s);
    }
}

// ---------------- node MLP (12 blocks x 32 rows) ---------------------------
__global__ __launch_bounds__(512)
void node_kernel(const float* __restrict__ nv, const float* __restrict__ nf,
                 const __bf16* __restrict__ wh1p, const __bf16* __restrict__ wh2p,
                 const __bf16* __restrict__ whlp,
                 const float* __restrict__ shift, const float* __restrict__ mi,
                 float* __restrict__ out) {
    __shared__ __align__(16) __bf16 xsb[32 * XS];   // [m_i | nf] 32x384
    __shared__ __align__(16) __bf16 h1b[32 * SS];
    __shared__ __align__(16) __bf16 h2b[32 * SS];
    const int tid  = threadIdx.x;
    const int wave = tid >> 6;
    const int lane = tid & 63;
    const int n0   = blockIdx.x * 32;

    // ---- stage xs = [m_i | nf]; vectors_out ----
#pragma unroll
    for (int p = tid; p < 32 * 256; p += 512) {
        int i = p >> 8, c = p & 255;
        xsb[i * XS + c] = (__bf16)mi[(n0 + i) * UU + c];
    }
#pragma unroll
    for (int p = tid; p < 32 * 128; p += 512) {
        int i = p >> 7, c = p & 127;
        xsb[i * XS + 256 + c] = (__bf16)nf[(n0 + i) * HH + c];
    }
#pragma unroll
    for (int p = tid; p < 32 * 96; p += 512) {
        int i = p / 96, j = p - i * 96;
        out[(n0 + i) * 96 + j] = nv[(n0 + i) * 96 + j]
                                 + shift[(n0 + i) * 96 + j] * (1.f / 383.f);
    }
    __syncthreads();

    // ---- h1 = silu(xs @ Wh1') ; h2 = silu(h1 @ Wh2') ----
    {
        const int m  = lane & 31;
        const int kh = lane >> 5;
        f32x16 acc = {};
        const __bf16* xr = xsb + m * XS + kh * 8;
        const __bf16* pb = wh1p + (wave * 32 + m) * 16 + kh * 8;
#pragma unroll
        for (int kt = 0; kt < 24; ++kt) {
            bf16v8 a0 = *(const bf16v8*)(xr + kt * 16);
            bf16v8 b  = *(const bf16v8*)(pb + kt * 4096);
            acc = __builtin_amdgcn_mfma_f32_32x32x16_bf16(a0, b, acc, 0, 0, 0);
        }
#pragma unroll
        for (int reg = 0; reg < 16; ++reg) {
            int row = (reg & 3) + 8 * (reg >> 2) + 4 * kh;
            h1b[row * SS + wave * 32 + m] = (__bf16)fast_silu(acc[reg]);
        }
    }
    __syncthreads();
    {
        const int m  = lane & 31;
        const int kh = lane >> 5;
        f32x16 acc = {};
        const __bf16* xr = h1b + m * SS + kh * 8;
        const __bf16* pb = wh2p + (wave * 32 + m) * 16 + kh * 8;
#pragma unroll
        for (int kt = 0; kt < 16; ++kt) {
            bf16v8 a0 = *(const bf16v8*)(xr + kt * 16);
            bf16v8 b  = *(const bf16v8*)(pb + kt * 4096);
            acc = __builtin_amdgcn_mfma_f32_32x32x16_bf16(a0, b, acc, 0, 0, 0);
        }
#pragma unroll
        for (int reg = 0; reg < 16; ++reg) {
            int row = (reg & 3) + 8 * (reg >> 2) + 4 * kh;
            h2b[row * SS + wave * 32 + m] = (__bf16)fast_silu(acc[reg]);
        }
    }
    __syncthreads();

    // ---- features_out = h2 @ Whl' + nf  (N=128, 16x16 MFMA, 8 n-tiles) ----
    {
        int col = lane & 15, q = lane >> 4;
        int n = wave * 16 + col;
#pragma unroll
        for (int mt = 0; mt < 2; ++mt) {
            f32x4 acc = {0.f, 0.f, 0.f, 0.f};
            const __bf16* xr = h2b + (mt * 16 + col) * SS + q * 8;
#pragma unroll
            for (int kt = 0; kt < 8; ++kt) {
                bf16v8 a = *(const bf16v8*)(xr + kt * 32);
                bf16v8 b = *(const bf16v8*)(whlp + kt * 4096 + n * 32 + q * 8);
                acc = __builtin_amdgcn_mfma_f32_16x16x32_bf16(a, b, acc, 0, 0, 0);
            }
#pragma unroll
            for (int i = 0; i < 4; ++i) {
                int row = n0 + mt * 16 + q * 4 + i;
                out[NN * 96 + row * HH + n] = acc[i] + nf[row * HH + n];
            }
        }
    }
}

// ------------------------------- launcher ----------------------------------
extern "C" void kernel_launch(void* const* d_in, const int* in_sizes, int n_in,
                              void* d_out, int out_size, void* d_ws, size_t ws_size,
                              hipStream_t stream) {
    const float* nv   = (const float*)d_in[0];
    const float* nf   = (const float*)d_in[1];
    const float* We1  = (const float*)d_in[2];
    const float* We2  = (const float*)d_in[3];
    const float* Wx1  = (const float*)d_in[4];
    const float* Wx2  = (const float*)d_in[5];
    const float* Wxl  = (const float*)d_in[6];
    const float* bxl  = (const float*)d_in[7];
    const float* Winf = (const float*)d_in[8];
    const float* Wh1  = (const float*)d_in[9];
    const float* Wh2  = (const float*)d_in[10];
    const float* Whl  = (const float*)d_in[11];
    float* out = (float*)d_out;

    char* ws = (char*)d_ws;
    float*  mi     = (float*)ws;                        // 384*256*4 = 393216
    float*  shift  = (float*)(ws + 393216);             // 384*96*4  = 147456
    float*  cvecg  = (float*)(ws + 540672);             // 393216
    float*  svecg  = (float*)(ws + 933888);             // 393216
    __bf16* we1p   = (__bf16*)(ws + 1327104);           // 16384 (k rows 0..31)
    __bf16* we2p   = (__bf16*)(ws + 1343488);           // 131072
    __bf16* wx1p   = (__bf16*)(ws + 1474560);           // 131072
    __bf16* wx2p   = (__bf16*)(ws + 1605632);           // 131072
    __bf16* wh1p   = (__bf16*)(ws + 1736704);           // 196608
    __bf16* wh2p   = (__bf16*)(ws + 1933312);           // 131072
    __bf16* wxlp   = (__bf16*)(ws + 2064384);           // 16384
    __bf16* whlp   = (__bf16*)(ws + 2080768);           // 65536

    repack_all<<<dim3(1240), 256, 0, stream>>>(We1, We2, Wx1, Wx2, Wh1, Wh2, Wxl, Whl,
                                               nf, we1p, we2p, wx1p, wx2p,
                                               wh1p, wh2p, wxlp, whlp, cvecg, svecg, mi);

    edge_kernel<<<dim3(NCHUNK, NN), 512, 0, stream>>>(nv, nf, we1p, we2p, wx1p, wx2p,
                                                      wxlp, bxl, Winf, cvecg, svecg,
                                                      shift, mi);
    node_kernel<<<dim3(12), 512, 0, stream>>>(nv, nf, wh1p, wh2p, whlp,
                                              shift, mi, out);
}